// Round 5
// baseline (263.422 us; speedup 1.0000x reference)
//
#include <hip/hip_runtime.h>
#include <hip/hip_bf16.h>
#include <stdint.h>
#include <stddef.h>

#define D_MODEL 4096
#define RANK    64
#define KC      256                 // fp32 k-elements per chunk
#define NCH     (D_MODEL / KC)      // 16
#define M_BLK   32

typedef __attribute__((ext_vector_type(4)))  float f32x4;
typedef __attribute__((ext_vector_type(16))) float f32x16;
typedef __attribute__((ext_vector_type(8)))  short bf16x8;

__device__ inline short f2bf1(float f) {
    union { __hip_bfloat16 t; short s; } c;
    c.t = __float2bfloat16(f);
    return c.s;
}
__device__ inline uint32_t pkbf(float a, float b) {
    union { __hip_bfloat162 t; uint32_t u; } c;
    c.t = __float22bfloat162_rn(make_float2(a, b));
    return c.u;
}

// ---------------------------------------------------------------------------
// Dequant + pack both weights into MFMA-fragment order.
// apk: for k-block kb (32 wide), n-tile n (16 ranks), lane l:
//      apk[((kb*4+n)*64+l)*8 + j] = a[16n+(l&15)][kb*32+(l>>4)*8+j]
// bpk: for col-block cb (32 cols), k-step ks (16 wide), lane l:
//      bpk[((cb*4+ks)*64+l)*8 + j] = b[cb*32+(l&31)][ks*16+(l>>5)*8+j]
// ---------------------------------------------------------------------------
__global__ __launch_bounds__(256) void dequant_pack_kernel(
        const int* __restrict__ qa, const float* __restrict__ qas,
        const int* __restrict__ qb, const float* __restrict__ qbs,
        short* __restrict__ apk, short* __restrict__ bpk) {
    const int idx = blockIdx.x * 256 + threadIdx.x;   // 0..32767
    const int l = idx & 63, t = idx >> 6;
    {   // a-side: t -> (kb, n)
        const int n = t & 3, kb = t >> 2;
        const int r = 16 * n + (l & 15);
        const int kbase = kb * 32 + ((l >> 4) << 3);
        const int* q = qa + (size_t)r * D_MODEL + kbase;
        const float s = qas[r * (D_MODEL / 32) + kb];
        bf16x8 o;
        #pragma unroll
        for (int j = 0; j < 8; ++j) o[j] = f2bf1((float)q[j] * s);
        *(bf16x8*)(apk + (size_t)idx * 8) = o;
    }
    {   // b-side: t -> (cb, ks)
        const int ks = t & 3, cb = t >> 2;
        const int d = cb * 32 + (l & 31);
        const int rbase = ks * 16 + ((l >> 5) << 3);
        const int* q = qb + (size_t)d * RANK + rbase;
        const float s = qbs[d * 2 + (ks >> 1)];
        bf16x8 o;
        #pragma unroll
        for (int j = 0; j < 8; ++j) o[j] = f2bf1((float)q[j] * s);
        *(bf16x8*)(bpk + (size_t)idx * 8) = o;
    }
}

// ---------------------------------------------------------------------------
// Fused: block = 32 token rows, 512 threads (8 waves), grid T/32 = 512.
// KC=256 -> LDS 39936 B -> 4 blocks/CU -> 32 waves/CU for latency hiding.
// Phase 1: double-buffered LDS staging of x, 8-wave split-K MFMA, one
//          barrier per chunk, 2-chunk register prefetch.
// Phase 2: two-round fp32 cross-wave reduce -> h bf16 in LDS.
// Phase 3: out = h @ b^T from packed bpk, 32x32x16 MFMA, coalesced stores.
// ---------------------------------------------------------------------------
__global__ __launch_bounds__(512, 8) void fused_kernel(
        const float* __restrict__ x, const short* __restrict__ apk,
        const short* __restrict__ bpk, float* __restrict__ out) {
    // smem: stage double buffer 2 x (32 rows x 256 bf16) = 32768 B,
    //       overlaid by red[4][32][68] f32 (34816 B) in phase 2;
    //       h_lds 32x80 bf16 = 5120 B after that region.
    __shared__ __align__(16) char smem[34816 + 5120];
    float* red   = (float*)smem;
    short* h_lds = (short*)(smem + 34816);

    const int tid  = threadIdx.x;
    const int lane = tid & 63;
    const int wave = tid >> 6;
    const int rb   = blockIdx.x * M_BLK;

    // staging: thread covers rows {0,8,16,24}+srow at float col scol (1 KB
    // contiguous per wave-instruction)
    const int srow = tid >> 6;               // 0..7  (== wave)
    const int scol = (tid & 63) << 2;        // 0,4,...,252
    const float* xb = x + (size_t)rb * D_MODEL;

    // ---- prologue: stage chunk 0, prefetch chunk 1 ----
    f32x4 xr[4];
    #pragma unroll
    for (int r = 0; r < 4; ++r)
        xr[r] = *(const f32x4*)(xb + (size_t)(r * 8 + srow) * D_MODEL + scol);
    #pragma unroll
    for (int r = 0; r < 4; ++r) {
        const int row = r * 8 + srow;
        int byte = row * 512 + (scol << 1);
        byte ^= (row & 7) << 4;
        union { uint32_t w[2]; uint2 u; } p;
        p.w[0] = pkbf(xr[r][0], xr[r][1]);
        p.w[1] = pkbf(xr[r][2], xr[r][3]);
        *(uint2*)(smem + byte) = p.u;
    }
    #pragma unroll
    for (int r = 0; r < 4; ++r)
        xr[r] = *(const f32x4*)(xb + (size_t)(r * 8 + srow) * D_MODEL + KC + scol);
    __syncthreads();

    f32x4 acc[2][4];
    #pragma unroll
    for (int m = 0; m < 2; ++m)
        #pragma unroll
        for (int n = 0; n < 4; ++n)
            acc[m][n] = (f32x4){0.f, 0.f, 0.f, 0.f};

    // ---- main K loop: one barrier per chunk; wave w owns k [w*32, w*32+32) ----
    for (int c = 0; c < NCH; ++c) {
        const char* sb = smem + (c & 1) * 16384;
        const int kin = wave * 32 + ((lane >> 4) << 3);
        bf16x8 af[2];
        #pragma unroll
        for (int m = 0; m < 2; ++m) {
            const int row = m * 16 + (lane & 15);
            int byte = row * 512 + (kin << 1);
            byte ^= (row & 7) << 4;
            af[m] = *(const bf16x8*)(sb + byte);
        }
        const int kbg = c * 8 + wave;          // global 32-wide k block
        #pragma unroll
        for (int n = 0; n < 4; ++n) {
            bf16x8 bf = *(const bf16x8*)(apk + ((size_t)((kbg * 4 + n) * 64 + lane) << 3));
            #pragma unroll
            for (int m = 0; m < 2; ++m)
                acc[m][n] = __builtin_amdgcn_mfma_f32_16x16x32_bf16(
                    af[m], bf, acc[m][n], 0, 0, 0);
        }
        if (c < NCH - 1) {
            char* sw = smem + ((c + 1) & 1) * 16384;
            #pragma unroll
            for (int r = 0; r < 4; ++r) {
                const int row = r * 8 + srow;
                int byte = row * 512 + (scol << 1);
                byte ^= (row & 7) << 4;
                union { uint32_t w[2]; uint2 u; } p;
                p.w[0] = pkbf(xr[r][0], xr[r][1]);
                p.w[1] = pkbf(xr[r][2], xr[r][3]);
                *(uint2*)(sw + byte) = p.u;
            }
            if (c < NCH - 2) {
                #pragma unroll
                for (int r = 0; r < 4; ++r)
                    xr[r] = *(const f32x4*)(xb + (size_t)(r * 8 + srow) * D_MODEL
                                            + (size_t)(c + 2) * KC + scol);
            }
        }
        __syncthreads();
    }

    // ---- phase 2: cross-wave reduction (red overlays stage) ----
    const int r4 = (lane >> 4) << 2;
    if (wave < 4) {
        #pragma unroll
        for (int m = 0; m < 2; ++m)
            #pragma unroll
            for (int n = 0; n < 4; ++n)
                #pragma unroll
                for (int j = 0; j < 4; ++j)
                    red[(wave * 32 + m * 16 + r4 + j) * 68 + n * 16 + (lane & 15)] =
                        acc[m][n][j];
    }
    __syncthreads();
    if (wave >= 4) {
        #pragma unroll
        for (int m = 0; m < 2; ++m)
            #pragma unroll
            for (int n = 0; n < 4; ++n)
                #pragma unroll
                for (int j = 0; j < 4; ++j)
                    red[((wave - 4) * 32 + m * 16 + r4 + j) * 68 + n * 16 + (lane & 15)] +=
                        acc[m][n][j];
    }
    __syncthreads();
    for (int e = tid; e < 32 * 64; e += 512) {
        const int r = e >> 6, cc = e & 63;
        float s = red[(0 * 32 + r) * 68 + cc] + red[(1 * 32 + r) * 68 + cc]
                + red[(2 * 32 + r) * 68 + cc] + red[(3 * 32 + r) * 68 + cc];
        h_lds[r * 80 + cc] = f2bf1(s);
    }
    __syncthreads();

    // ---- phase 3: out[32][4096] = h @ b^T; wave w -> cols [w*512, +512) ----
    bf16x8 hf[4];
    #pragma unroll
    for (int ks = 0; ks < 4; ++ks)
        hf[ks] = *(const bf16x8*)(h_lds + (lane & 31) * 80 + ks * 16 + ((lane >> 5) << 3));

    #pragma unroll
    for (int n = 0; n < 16; ++n) {
        const int cb32 = wave * 16 + n;
        const int col  = cb32 * 32 + (lane & 31);
        f32x16 a2;
        #pragma unroll
        for (int j = 0; j < 16; ++j) a2[j] = 0.f;
        #pragma unroll
        for (int ks = 0; ks < 4; ++ks) {
            bf16x8 bf = *(const bf16x8*)(bpk + ((size_t)((cb32 * 4 + ks) * 64 + lane) << 3));
            a2 = __builtin_amdgcn_mfma_f32_32x32x16_bf16(hf[ks], bf, a2, 0, 0, 0);
        }
        #pragma unroll
        for (int reg = 0; reg < 16; ++reg) {
            const int r = (reg & 3) + 8 * (reg >> 2) + ((lane >> 5) << 2);
            out[(size_t)(rb + r) * D_MODEL + col] = a2[reg];
        }
    }
}

// ---------------------------------------------------------------------------
extern "C" void kernel_launch(void* const* d_in, const int* in_sizes, int n_in,
                              void* d_out, int out_size, void* d_ws, size_t ws_size,
                              hipStream_t stream) {
    (void)n_in; (void)out_size; (void)ws_size;
    const float* x   = (const float*)d_in[0];
    const int*   qa  = (const int*)d_in[1];
    const float* qas = (const float*)d_in[2];
    const int*   qb  = (const int*)d_in[3];
    const float* qbs = (const float*)d_in[4];
    float* out = (float*)d_out;

    const int T = in_sizes[0] / D_MODEL;   // 16384

    short* apk = (short*)d_ws;                       // 64*4096 bf16 packed
    short* bpk = apk + (size_t)RANK * D_MODEL;       // 4096*64 bf16 packed

    dequant_pack_kernel<<<128, 256, 0, stream>>>(qa, qas, qb, qbs, apk, bpk);
    fused_kernel<<<T / M_BLK, 512, 0, stream>>>(x, apk, bpk, out);
}

// Round 6
// 155.247 us; speedup vs baseline: 1.6968x; 1.6968x over previous
//
#include <hip/hip_runtime.h>
#include <hip/hip_bf16.h>
#include <stdint.h>
#include <stddef.h>

#define D_MODEL 4096
#define RANK    64
#define KC      512                 // fp32 k-elements per chunk
#define NCH     (D_MODEL / KC)      // 8
#define M_BLK   16

typedef __attribute__((ext_vector_type(4)))  float f32x4;
typedef __attribute__((ext_vector_type(8)))  short bf16x8;

__device__ inline short f2bf1(float f) {
    union { __hip_bfloat16 t; short s; } c;
    c.t = __float2bfloat16(f);
    return c.s;
}
__device__ inline uint32_t pkbf(float a, float b) {
    union { __hip_bfloat162 t; uint32_t u; } c;
    c.t = __float22bfloat162_rn(make_float2(a, b));
    return c.u;
}

// ---------------------------------------------------------------------------
// Dequant + pack both weights into MFMA-fragment order.
// apk (16x16x32 B-frag, 16-rank n-tiles, 32-wide k-blocks):
//   apk[((kb*4+n)*64+l)*8 + j] = a[16n+(l&15)][kb*32+(l>>4)*8+j]
// bpk (16x16x32 B-frag, 16-col tiles, 32-wide k(rank)-steps):
//   bpk[((cb*2+ks)*64+l)*8 + j] = b[cb*16+(l&15)][ks*32+(l>>4)*8+j]
// Every fragment load in the fused kernel is 64 lanes x 16 B contiguous.
// ---------------------------------------------------------------------------
__global__ __launch_bounds__(256) void dequant_pack_kernel(
        const int* __restrict__ qa, const float* __restrict__ qas,
        const int* __restrict__ qb, const float* __restrict__ qbs,
        short* __restrict__ apk, short* __restrict__ bpk) {
    const int idx = blockIdx.x * 256 + threadIdx.x;   // 0..32767
    const int l = idx & 63, t = idx >> 6;             // t: 0..511
    {   // a-side: t -> (kb 0..127, n 0..3)
        const int n = t & 3, kb = t >> 2;
        const int r = 16 * n + (l & 15);
        const int kbase = kb * 32 + ((l >> 4) << 3);
        const int* q = qa + (size_t)r * D_MODEL + kbase;
        const float s = qas[r * (D_MODEL / 32) + kb];
        bf16x8 o;
        #pragma unroll
        for (int j = 0; j < 8; ++j) o[j] = f2bf1((float)q[j] * s);
        *(bf16x8*)(apk + (size_t)idx * 8) = o;
    }
    {   // b-side: t -> (cb 0..255, ks 0..1)
        const int ks = t & 1, cb = t >> 1;
        const int d = cb * 16 + (l & 15);
        const int rbase = ks * 32 + ((l >> 4) << 3);
        const int* q = qb + (size_t)d * RANK + rbase;
        const float s = qbs[d * 2 + ks];
        bf16x8 o;
        #pragma unroll
        for (int j = 0; j < 8; ++j) o[j] = f2bf1((float)q[j] * s);
        *(bf16x8*)(bpk + (size_t)idx * 8) = o;
    }
}

// ---------------------------------------------------------------------------
// Fused: block = 16 token rows, 256 threads (4 waves), grid T/16 = 1024
// -> 4 blocks/CU (LDS 35.3 KB), 4 independent barrier domains per CU.
// Phase 1: double-buffered XOR-swizzled LDS stage of x (bf16), split-K-4
//          MFMA (wave w owns k-slice [w*128,+128) per chunk), one barrier
//          per chunk, 2-chunk register prefetch.
// Phase 2: fp32 cross-wave reduce (red overlays stage) -> h bf16 in LDS.
// Phase 3: out = h @ b^T via 16x16x32 MFMA from packed bpk.
// ---------------------------------------------------------------------------
__global__ __launch_bounds__(256, 4) void fused_kernel(
        const float* __restrict__ x, const short* __restrict__ apk,
        const short* __restrict__ bpk, float* __restrict__ out) {
    // stage double buffer: 2 x (16 rows x 512 bf16) = 32768 B,
    // overlaid in phase 2 by red[4][16][68] f32 (17408 B); h_lds after.
    __shared__ __align__(16) char smem[32768 + 2560];
    float* red   = (float*)smem;
    short* h_lds = (short*)(smem + 32768);

    const int tid  = threadIdx.x;
    const int lane = tid & 63;
    const int wave = tid >> 6;
    const int rb   = blockIdx.x * M_BLK;

    // staging: round r covers rows {0,2,...,14}+srow; thread reads f32x4 at scol
    const int srow = tid >> 7;               // 0..1
    const int scol = (tid & 127) << 2;       // f32 col 0,4,...,508
    const float* xb = x + (size_t)rb * D_MODEL;

    // ---- prologue: stage chunk 0, prefetch chunk 1 ----
    f32x4 xr[8];
    #pragma unroll
    for (int r = 0; r < 8; ++r)
        xr[r] = *(const f32x4*)(xb + (size_t)(r * 2 + srow) * D_MODEL + scol);
    #pragma unroll
    for (int r = 0; r < 8; ++r) {
        const int row = r * 2 + srow;
        int byte = row * 1024 + (scol << 1);
        byte ^= (row & 7) << 4;
        union { uint32_t w[2]; uint2 u; } p;
        p.w[0] = pkbf(xr[r][0], xr[r][1]);
        p.w[1] = pkbf(xr[r][2], xr[r][3]);
        *(uint2*)(smem + byte) = p.u;
    }
    #pragma unroll
    for (int r = 0; r < 8; ++r)
        xr[r] = *(const f32x4*)(xb + (size_t)(r * 2 + srow) * D_MODEL + KC + scol);
    __syncthreads();

    f32x4 acc[4];
    #pragma unroll
    for (int n = 0; n < 4; ++n) acc[n] = (f32x4){0.f, 0.f, 0.f, 0.f};

    // ---- main K loop: one barrier per chunk; wave w owns k [w*128, +128) ----
    for (int c = 0; c < NCH; ++c) {
        const char* sb = smem + (c & 1) * 16384;
        #pragma unroll
        for (int s = 0; s < 4; ++s) {
            const int kin = wave * 128 + s * 32 + ((lane >> 4) << 3);
            const int row = lane & 15;
            int byte = row * 1024 + (kin << 1);
            byte ^= (row & 7) << 4;
            bf16x8 af = *(const bf16x8*)(sb + byte);
            const int kbg = c * 16 + wave * 4 + s;      // global 32-wide k block
            #pragma unroll
            for (int n = 0; n < 4; ++n) {
                bf16x8 bf = *(const bf16x8*)(apk + ((size_t)((kbg * 4 + n) * 64 + lane) << 3));
                acc[n] = __builtin_amdgcn_mfma_f32_16x16x32_bf16(af, bf, acc[n], 0, 0, 0);
            }
        }
        if (c < NCH - 1) {
            char* sw = smem + ((c + 1) & 1) * 16384;
            #pragma unroll
            for (int r = 0; r < 8; ++r) {
                const int row = r * 2 + srow;
                int byte = row * 1024 + (scol << 1);
                byte ^= (row & 7) << 4;
                union { uint32_t w[2]; uint2 u; } p;
                p.w[0] = pkbf(xr[r][0], xr[r][1]);
                p.w[1] = pkbf(xr[r][2], xr[r][3]);
                *(uint2*)(sw + byte) = p.u;
            }
            if (c < NCH - 2) {
                #pragma unroll
                for (int r = 0; r < 8; ++r)
                    xr[r] = *(const f32x4*)(xb + (size_t)(r * 2 + srow) * D_MODEL
                                            + (size_t)(c + 2) * KC + scol);
            }
        }
        __syncthreads();
    }

    // ---- phase 2: cross-wave reduction (red overlays stage) ----
    const int r4 = (lane >> 4) << 2;
    #pragma unroll
    for (int n = 0; n < 4; ++n)
        #pragma unroll
        for (int j = 0; j < 4; ++j)
            red[(wave * 16 + r4 + j) * 68 + n * 16 + (lane & 15)] = acc[n][j];
    __syncthreads();
    for (int e = tid; e < 16 * 64; e += 256) {
        const int r = e >> 6, cc = e & 63;
        float s = red[(0 * 16 + r) * 68 + cc] + red[(1 * 16 + r) * 68 + cc]
                + red[(2 * 16 + r) * 68 + cc] + red[(3 * 16 + r) * 68 + cc];
        h_lds[r * 80 + cc] = f2bf1(s);
    }
    __syncthreads();

    // ---- phase 3: out[16][4096] = h @ b^T; wave w -> cols [w*1024, +1024) ----
    bf16x8 hf[2];
    #pragma unroll
    for (int ks = 0; ks < 2; ++ks)
        hf[ks] = *(const bf16x8*)(h_lds + (lane & 15) * 80 + ks * 32 + ((lane >> 4) << 3));

    #pragma unroll 4
    for (int n = 0; n < 64; ++n) {
        const int cb = wave * 64 + n;                  // 16-col tile index
        f32x4 a2 = (f32x4){0.f, 0.f, 0.f, 0.f};
        #pragma unroll
        for (int ks = 0; ks < 2; ++ks) {
            bf16x8 bf = *(const bf16x8*)(bpk + ((size_t)((cb * 2 + ks) * 64 + lane) << 3));
            a2 = __builtin_amdgcn_mfma_f32_16x16x32_bf16(hf[ks], bf, a2, 0, 0, 0);
        }
        const int col = cb * 16 + (lane & 15);
        #pragma unroll
        for (int j = 0; j < 4; ++j)
            out[(size_t)(rb + r4 + j) * D_MODEL + col] = a2[j];
    }
}

// ---------------------------------------------------------------------------
extern "C" void kernel_launch(void* const* d_in, const int* in_sizes, int n_in,
                              void* d_out, int out_size, void* d_ws, size_t ws_size,
                              hipStream_t stream) {
    (void)n_in; (void)out_size; (void)ws_size;
    const float* x   = (const float*)d_in[0];
    const int*   qa  = (const int*)d_in[1];
    const float* qas = (const float*)d_in[2];
    const int*   qb  = (const int*)d_in[3];
    const float* qbs = (const float*)d_in[4];
    float* out = (float*)d_out;

    const int T = in_sizes[0] / D_MODEL;   // 16384

    short* apk = (short*)d_ws;                       // 64*4096 bf16 packed
    short* bpk = apk + (size_t)RANK * D_MODEL;       // 4096*64 bf16 packed

    dequant_pack_kernel<<<128, 256, 0, stream>>>(qa, qas, qb, qbs, apk, bpk);
    fused_kernel<<<T / M_BLK, 256, 0, stream>>>(x, apk, bpk, out);
}